// Round 1
// baseline (233.483 us; speedup 1.0000x reference)
//
#include <hip/hip_runtime.h>
#include <hip/hip_bf16.h>

#define NODES 256

// ---------------------------------------------------------------------------
// Prologue: compute Akima node slopes s[0..255] per the reference recurrence,
// then pack per-interval coefficients tab[i] = {v[i], v[i+1], s[i], s[i+1]}.
// One block, 256 threads. Runs once per launch into d_ws.
// ---------------------------------------------------------------------------
__global__ __launch_bounds__(256) void akima_prologue(
    const float* __restrict__ value, float4* __restrict__ tab) {
  __shared__ float me[NODES + 3];   // extended slopes, len 259
  __shared__ float s[NODES];
  const int t = threadIdx.x;
  const float h = 1.0f / 255.0f;    // (D1-D0)/(n-1) rounded to f32, as in ref

  // m[i] = (v[i+1]-v[i])/h  -> me[i+2], i in [0,254]
  if (t < NODES - 1) me[t + 2] = (value[t + 1] - value[t]) / h;
  __syncthreads();

  if (t == 0) {
    float m0 = me[2], m1 = me[3];
    float m_m1 = 2.0f * m0 - m1;
    me[1] = m_m1;
    me[0] = 2.0f * m_m1 - m0;
    float mL = me[NODES];      // m[254]
    float mL1 = me[NODES - 1]; // m[253]
    float m_p1 = 2.0f * mL - mL1;
    me[NODES + 1] = m_p1;
    me[NODES + 2] = 2.0f * m_p1 - mL;
  }
  __syncthreads();

  {
    float w1 = fabsf(me[t + 3] - me[t + 2]);
    float w2 = fabsf(me[t + 1] - me[t]);
    float denom = w1 + w2;
    float sv;
    if (denom > 0.0f)
      sv = (w1 * me[t + 1] + w2 * me[t + 2]) / denom;
    else
      sv = 0.5f * (me[t + 1] + me[t + 2]);
    s[t] = sv;
  }
  __syncthreads();

  if (t < NODES - 1)
    tab[t] = make_float4(value[t], value[t + 1], s[t], s[t + 1]);
}

// ---------------------------------------------------------------------------
// Main: memory-bound elementwise eval. float4 vectorized grid-stride loop,
// 4 KB coefficient table staged in LDS, one ds_read_b128 gather per element.
// ---------------------------------------------------------------------------
__global__ __launch_bounds__(256) void akima_main(
    const float* __restrict__ in, const float4* __restrict__ tab,
    float* __restrict__ out, long long n, long long n4) {
  __shared__ float4 stab[NODES - 1];
  if (threadIdx.x < NODES - 1) stab[threadIdx.x] = tab[threadIdx.x];
  __syncthreads();

  const float h = 1.0f / 255.0f;
  const float4* __restrict__ in4 = reinterpret_cast<const float4*>(in);
  float4* __restrict__ out4 = reinterpret_cast<float4*>(out);

  const long long stride = (long long)gridDim.x * blockDim.x;
  long long i0 = (long long)blockIdx.x * blockDim.x + threadIdx.x;

  for (long long i = i0; i < n4; i += stride) {
    float4 x4 = in4[i];
    float xs[4] = {x4.x, x4.y, x4.z, x4.w};
    float r[4];
#pragma unroll
    for (int j = 0; j < 4; ++j) {
      float x = fminf(fmaxf(xs[j], 0.0f), 1.0f);  // clip(input, D0, D1)
      float tt = x / h;                           // IEEE div, matches ref
      int idx = (int)floorf(tt);
      idx = min(max(idx, 0), NODES - 2);
      float u = tt - (float)idx;
      float4 c = stab[idx];                       // {v0, v1, s0, s1}
      float u2 = u * u;
      float u3 = u2 * u;
      float h00 = 2.0f * u3 - 3.0f * u2 + 1.0f;
      float h10 = u3 - 2.0f * u2 + u;
      float h01 = -2.0f * u3 + 3.0f * u2;
      float h11 = u3 - u2;
      r[j] = h00 * c.x + h10 * h * c.z + h01 * c.y + h11 * h * c.w;
    }
    out4[i] = make_float4(r[0], r[1], r[2], r[3]);
  }

  // Scalar tail (n not divisible by 4) — no-op for the bench shape.
  for (long long i = n4 * 4 + i0; i < n; i += stride) {
    float x = fminf(fmaxf(in[i], 0.0f), 1.0f);
    float tt = x / h;
    int idx = (int)floorf(tt);
    idx = min(max(idx, 0), NODES - 2);
    float u = tt - (float)idx;
    float4 c = stab[idx];
    float u2 = u * u;
    float u3 = u2 * u;
    float h00 = 2.0f * u3 - 3.0f * u2 + 1.0f;
    float h10 = u3 - 2.0f * u2 + u;
    float h01 = -2.0f * u3 + 3.0f * u2;
    float h11 = u3 - u2;
    out[i] = h00 * c.x + h10 * h * c.z + h01 * c.y + h11 * h * c.w;
  }
}

extern "C" void kernel_launch(void* const* d_in, const int* in_sizes, int n_in,
                              void* d_out, int out_size, void* d_ws, size_t ws_size,
                              hipStream_t stream) {
  const float* in = (const float*)d_in[0];     // (32,1024,1024) f32
  const float* value = (const float*)d_in[1];  // (256,) f32
  float* out = (float*)d_out;
  float4* tab = (float4*)d_ws;                 // 255 * 16 B = 4080 B scratch

  long long n = (long long)in_sizes[0];
  long long n4 = n / 4;

  akima_prologue<<<1, 256, 0, stream>>>(value, tab);

  long long want = (n4 + 255) / 256;
  int blocks = (int)(want < 2048 ? (want > 0 ? want : 1) : 2048);
  akima_main<<<blocks, 256, 0, stream>>>(in, tab, out, n, n4);
}

// Round 3
// 230.305 us; speedup vs baseline: 1.0138x; 1.0138x over previous
//
#include <hip/hip_runtime.h>
#include <hip/hip_bf16.h>

#define NODES 256

// ---------------------------------------------------------------------------
// Fused single kernel. Each block rebuilds the 255-entry Akima coefficient
// table {v0,v1,s0,s1} in LDS from `value` (1 KB, L2-broadcast — ~1 us), then
// runs a float4-vectorized grid-stride eval loop. No prologue kernel, no d_ws.
// 2048 blocks x 256 threads = 8 blocks/CU, 32 waves/CU (max occupancy;
// LDS ~7.3 KB/block, low VGPR).
// ---------------------------------------------------------------------------
__global__ __launch_bounds__(256) void akima_fused(
    const float* __restrict__ in, const float* __restrict__ value,
    float* __restrict__ out, long long n, long long n4) {
  __shared__ float val[NODES];
  __shared__ float me[NODES + 3];   // extended slopes, len 259
  __shared__ float s[NODES];
  __shared__ float4 stab[NODES - 1];

  const int t = threadIdx.x;
  const float h = 1.0f / 255.0f;    // (D1-D0)/(n-1) rounded to f32, as in ref

  // --- table build (matches reference _akima_node_slopes in f32) ---
  val[t] = value[t];
  __syncthreads();
  if (t < NODES - 1) me[t + 2] = (val[t + 1] - val[t]) / h;  // m[i]
  __syncthreads();
  if (t == 0) {
    float m0 = me[2], m1 = me[3];
    float m_m1 = 2.0f * m0 - m1;
    me[1] = m_m1;
    me[0] = 2.0f * m_m1 - m0;
    float mL = me[NODES];       // m[254]
    float mL1 = me[NODES - 1];  // m[253]
    float m_p1 = 2.0f * mL - mL1;
    me[NODES + 1] = m_p1;
    me[NODES + 2] = 2.0f * m_p1 - mL;
  }
  __syncthreads();
  {
    float w1 = fabsf(me[t + 3] - me[t + 2]);
    float w2 = fabsf(me[t + 1] - me[t]);
    float denom = w1 + w2;
    s[t] = (denom > 0.0f) ? (w1 * me[t + 1] + w2 * me[t + 2]) / denom
                          : 0.5f * (me[t + 1] + me[t + 2]);
  }
  __syncthreads();
  if (t < NODES - 1) stab[t] = make_float4(val[t], val[t + 1], s[t], s[t + 1]);
  __syncthreads();

  // --- streaming eval ---
  const float4* __restrict__ in4 = reinterpret_cast<const float4*>(in);
  float4* __restrict__ out4 = reinterpret_cast<float4*>(out);
  const long long stride = (long long)gridDim.x * blockDim.x;
  const long long i0 = (long long)blockIdx.x * blockDim.x + t;

  for (long long i = i0; i < n4; i += stride) {
    float4 x4 = in4[i];
    float xs[4] = {x4.x, x4.y, x4.z, x4.w};
    float r[4];
#pragma unroll
    for (int j = 0; j < 4; ++j) {
      float x = fminf(fmaxf(xs[j], 0.0f), 1.0f);  // v_med3 clamp
      float tt = x * 255.0f;                      // == x/h to <=1 ulp; no div
      int idx = (int)floorf(tt);
      idx = min(max(idx, 0), NODES - 2);
      float u = tt - (float)idx;
      float4 c = stab[idx];                       // one ds_read_b128 gather
      float u2 = u * u;
      float u3 = u2 * u;
      float h00 = 2.0f * u3 - 3.0f * u2 + 1.0f;
      float h10 = u3 - 2.0f * u2 + u;
      float h01 = -2.0f * u3 + 3.0f * u2;
      float h11 = u3 - u2;
      r[j] = h00 * c.x + h10 * h * c.z + h01 * c.y + h11 * h * c.w;
    }
    out4[i] = make_float4(r[0], r[1], r[2], r[3]);
  }

  // scalar tail (n % 4) — no-op at the bench shape
  for (long long i = n4 * 4 + i0; i < n; i += stride) {
    float x = fminf(fmaxf(in[i], 0.0f), 1.0f);
    float tt = x * 255.0f;
    int idx = (int)floorf(tt);
    idx = min(max(idx, 0), NODES - 2);
    float u = tt - (float)idx;
    float4 c = stab[idx];
    float u2 = u * u;
    float u3 = u2 * u;
    float h00 = 2.0f * u3 - 3.0f * u2 + 1.0f;
    float h10 = u3 - 2.0f * u2 + u;
    float h01 = -2.0f * u3 + 3.0f * u2;
    float h11 = u3 - u2;
    out[i] = h00 * c.x + h10 * h * c.z + h01 * c.y + h11 * h * c.w;
  }
}

extern "C" void kernel_launch(void* const* d_in, const int* in_sizes, int n_in,
                              void* d_out, int out_size, void* d_ws, size_t ws_size,
                              hipStream_t stream) {
  const float* in = (const float*)d_in[0];     // (32,1024,1024) f32
  const float* value = (const float*)d_in[1];  // (256,) f32
  float* out = (float*)d_out;

  long long n = (long long)in_sizes[0];
  long long n4 = n / 4;

  long long want = (n4 + 255) / 256;
  int blocks = (int)(want < 2048 ? (want > 0 ? want : 1) : 2048);
  akima_fused<<<blocks, 256, 0, stream>>>(in, value, out, n, n4);
}

// Round 5
// 227.845 us; speedup vs baseline: 1.0247x; 1.0108x over previous
//
#include <hip/hip_runtime.h>
#include <hip/hip_bf16.h>

#define NODES 256

typedef float f32x4 __attribute__((ext_vector_type(4)));  // native clang vector
                                                          // (nontemporal-builtin OK)

// ---------------------------------------------------------------------------
// Prologue (1 block): Akima node slopes per the reference recurrence, packed
// as per-interval float4 tab[i] = {v[i], v[i+1], s[i], s[i+1]} into d_ws.
// ---------------------------------------------------------------------------
__global__ __launch_bounds__(256) void akima_prologue(
    const float* __restrict__ value, float4* __restrict__ tab) {
  __shared__ float me[NODES + 3];
  __shared__ float s[NODES];
  const int t = threadIdx.x;
  const float h = 1.0f / 255.0f;

  if (t < NODES - 1) me[t + 2] = (value[t + 1] - value[t]) / h;
  __syncthreads();
  if (t == 0) {
    float m0 = me[2], m1 = me[3];
    float m_m1 = 2.0f * m0 - m1;
    me[1] = m_m1;
    me[0] = 2.0f * m_m1 - m0;
    float mL = me[NODES], mL1 = me[NODES - 1];
    float m_p1 = 2.0f * mL - mL1;
    me[NODES + 1] = m_p1;
    me[NODES + 2] = 2.0f * m_p1 - mL;
  }
  __syncthreads();
  {
    float w1 = fabsf(me[t + 3] - me[t + 2]);
    float w2 = fabsf(me[t + 1] - me[t]);
    float denom = w1 + w2;
    s[t] = (denom > 0.0f) ? (w1 * me[t + 1] + w2 * me[t + 2]) / denom
                          : 0.5f * (me[t + 1] + me[t + 2]);
  }
  __syncthreads();
  if (t < NODES - 1)
    tab[t] = make_float4(value[t], value[t + 1], s[t], s[t + 1]);
}

// ---------------------------------------------------------------------------
// Main. Gather bottleneck split across two independent pipes:
//   elems 0,2 -> LDS table (DS unit), elems 1,3 -> L1-resident global table
//   (TA/TCP unit). Random-idx bank conflicts are inherent (Poisson), so
//   halving each pipe's traffic ~halves the serialization. Streaming in/out
//   is nontemporal so the 4 KB table stays L1-resident.
// ---------------------------------------------------------------------------
__device__ __forceinline__ float akima_eval(float x, const float4& c) {
  const float h = 1.0f / 255.0f;
  float tt = fminf(fmaxf(x, 0.0f), 1.0f) * 255.0f;
  int idx = min(max((int)tt, 0), NODES - 2);
  float u = tt - (float)idx;
  float u2 = u * u;
  float u3 = u2 * u;
  float h00 = 2.0f * u3 - 3.0f * u2 + 1.0f;
  float h10 = u3 - 2.0f * u2 + u;
  float h01 = -2.0f * u3 + 3.0f * u2;
  float h11 = u3 - u2;
  return h00 * c.x + h10 * h * c.z + h01 * c.y + h11 * h * c.w;
}

__device__ __forceinline__ int akima_idx(float x) {
  float tt = fminf(fmaxf(x, 0.0f), 1.0f) * 255.0f;
  return min(max((int)tt, 0), NODES - 2);
}

__global__ __launch_bounds__(256) void akima_main(
    const float* __restrict__ in, const float4* __restrict__ gtab,
    float* __restrict__ out, long long n, long long n4) {
  __shared__ float4 stab[NODES - 1];
  if (threadIdx.x < NODES - 1) stab[threadIdx.x] = gtab[threadIdx.x];
  __syncthreads();

  const f32x4* __restrict__ in4 = reinterpret_cast<const f32x4*>(in);
  f32x4* __restrict__ out4 = reinterpret_cast<f32x4*>(out);
  const long long stride = (long long)gridDim.x * blockDim.x;
  const long long i0 = (long long)blockIdx.x * blockDim.x + threadIdx.x;

  for (long long i = i0; i < n4; i += stride) {
    f32x4 x4 = __builtin_nontemporal_load(&in4[i]);

    // Issue all four gathers up front; alternate pipes.
    int ia = akima_idx(x4.x);
    int ib = akima_idx(x4.y);
    int ic = akima_idx(x4.z);
    int id = akima_idx(x4.w);
    float4 ca = stab[ia];   // DS pipe
    float4 cb = gtab[ib];   // TA/L1 pipe
    float4 cc = stab[ic];   // DS pipe
    float4 cd = gtab[id];   // TA/L1 pipe

    f32x4 r;
    r.x = akima_eval(x4.x, ca);
    r.y = akima_eval(x4.y, cb);
    r.z = akima_eval(x4.z, cc);
    r.w = akima_eval(x4.w, cd);
    __builtin_nontemporal_store(r, &out4[i]);
  }

  // scalar tail (n % 4) — no-op at the bench shape
  for (long long i = n4 * 4 + i0; i < n; i += stride) {
    float x = in[i];
    float4 c = stab[akima_idx(x)];
    out[i] = akima_eval(x, c);
  }
}

extern "C" void kernel_launch(void* const* d_in, const int* in_sizes, int n_in,
                              void* d_out, int out_size, void* d_ws, size_t ws_size,
                              hipStream_t stream) {
  const float* in = (const float*)d_in[0];     // (32,1024,1024) f32
  const float* value = (const float*)d_in[1];  // (256,) f32
  float* out = (float*)d_out;
  float4* tab = (float4*)d_ws;                 // 255 * 16 B = 4080 B scratch

  long long n = (long long)in_sizes[0];
  long long n4 = n / 4;

  akima_prologue<<<1, 256, 0, stream>>>(value, tab);

  long long want = (n4 + 255) / 256;
  int blocks = (int)(want < 2048 ? (want > 0 ? want : 1) : 2048);
  akima_main<<<blocks, 256, 0, stream>>>(in, tab, out, n, n4);
}